// Round 10
// baseline (284.933 us; speedup 1.0000x reference)
//
#include <hip/hip_runtime.h>
#include <hip/hip_fp16.h>
#include <math.h>

#define N_USERS   50000
#define N_ENT     100000
#define N_EDGES   2000000
#define NNZ       1000000
#define DIM       64
#define HALF_E    (N_ENT / 2)
#define HALF_U    (N_USERS / 2)

#define GA      512                    // blocks per side for bucket hist/scatter
#define NB_E    391                    // coarse buckets (256 keys each) entity
#define NB_U    196                    // user
#define NALL_E  (NB_E * GA)            // 200192
#define NALL_U  (NB_U * GA)            // 100352
#define NALL    (NALL_E + NALL_U)      // 300544
#define NB_SCAN (NALL / 512)           // 587 (exact)
#define CAP_D   6400                   // bucket capacity (mean 5120 + 18 sigma)

// ---------------- helpers ----------------

typedef unsigned u32x4 __attribute__((ext_vector_type(4)));
typedef float    f32x4 __attribute__((ext_vector_type(4)));

__device__ inline unsigned pack_h2(float x, float y) {
    unsigned lo = __half_as_ushort(__float2half_rn(x));
    unsigned hi = __half_as_ushort(__float2half_rn(y));
    return lo | (hi << 16);
}

__device__ inline float2 unpack_h2(unsigned u) {
    __half2 h = *reinterpret_cast<__half2*>(&u);
    return __half22float2(h);
}

__device__ inline __half2 bits_h2(unsigned u) { return *reinterpret_cast<__half2*>(&u); }

__device__ inline __half2 shfl_h2(__half2 v, int o) {
    int x = *reinterpret_cast<int*>(&v);
    x = __shfl_xor(x, o, 64);
    return *reinterpret_cast<__half2*>(&x);
}

// non-temporal 16B helpers (streaming data must not evict the gather table)
__device__ inline uint4 nt_load_u4(const uint4* p) {
    u32x4 v = __builtin_nontemporal_load((const u32x4*)p);
    uint4 r; r.x = v.x; r.y = v.y; r.z = v.z; r.w = v.w; return r;
}
__device__ inline void nt_store_u4(uint4* p, uint4 v) {
    u32x4 t; t.x = v.x; t.y = v.y; t.z = v.z; t.w = v.w;
    __builtin_nontemporal_store(t, (u32x4*)p);
}
__device__ inline float4 nt_load_f4(const float4* p) {
    f32x4 v = __builtin_nontemporal_load((const f32x4*)p);
    float4 r; r.x = v.x; r.y = v.y; r.z = v.z; r.w = v.w; return r;
}
__device__ inline void nt_store_f4(float4* p, float4 v) {
    f32x4 t; t.x = v.x; t.y = v.y; t.z = v.z; t.w = v.w;
    __builtin_nontemporal_store(t, (f32x4*)p);
}

// f32 -> packed fp16 (uint4 = 8 halves from 2 float4)
__global__ void f32_to_f16(const float4* __restrict__ in, uint4* __restrict__ out, int n4) {
    int i = blockIdx.x * blockDim.x + threadIdx.x;
    if (i < n4) {
        float4 a = in[2 * i], b = in[2 * i + 1];
        uint4 o;
        o.x = pack_h2(a.x, a.y);
        o.y = pack_h2(a.z, a.w);
        o.z = pack_h2(b.x, b.y);
        o.w = pack_h2(b.z, b.w);
        out[i] = o;
    }
}

// ---------------- CSR build: two-level LDS counting sort (no global atomics) ----------------
// Coarse bucket = key >> 8. E and U sides merged per pass.

__global__ __launch_bounds__(256) void bucket_hist_both(
    const int* __restrict__ head, const int* __restrict__ irows, int* __restrict__ bh) {
    __shared__ int h[NB_E];
    bool isE = blockIdx.x < GA;
    int b = isE ? blockIdx.x : blockIdx.x - GA;
    const int* key = isE ? head : irows;
    int n = isE ? N_EDGES : NNZ;
    int nbuck = isE ? NB_E : NB_U;
    int base = isE ? 0 : NALL_E;
    for (int t = threadIdx.x; t < nbuck; t += 256) h[t] = 0;
    __syncthreads();
    int chunk = (n + GA - 1) / GA;
    int s = b * chunk;
    int e = n < s + chunk ? n : s + chunk;
    for (int i = s + threadIdx.x; i < e; i += 256)
        atomicAdd(&h[key[i] >> 8], 1);
    __syncthreads();
    for (int t = threadIdx.x; t < nbuck; t += 256)
        bh[base + t * GA + b] = h[t];
}

// 3-kernel exclusive scan over the concatenated count array (512-thr blocks)
__global__ void scan_partial(const int* __restrict__ cnt, int n, int* __restrict__ bsum) {
    __shared__ int sd[512];
    int tid = threadIdx.x, i = blockIdx.x * 512 + tid;
    sd[tid] = (i < n) ? cnt[i] : 0;
    __syncthreads();
    for (int s = 256; s > 0; s >>= 1) {
        if (tid < s) sd[tid] += sd[tid + s];
        __syncthreads();
    }
    if (tid == 0) bsum[blockIdx.x] = sd[0];
}

__global__ void scan_bsum(int* bsum, int nb) {
    __shared__ int sd[1024];
    int tid = threadIdx.x;
    int v = (tid < nb) ? bsum[tid] : 0;
    sd[tid] = v;
    __syncthreads();
    for (int o = 1; o < 1024; o <<= 1) {
        int t = (tid >= o) ? sd[tid - o] : 0;
        __syncthreads();
        sd[tid] += t;
        __syncthreads();
    }
    if (tid < nb) bsum[tid] = sd[tid] - v;  // exclusive
}

__global__ void scan_final(const int* __restrict__ cnt, int n,
                           const int* __restrict__ bsum, int* __restrict__ rp) {
    __shared__ int sd[512];
    int tid = threadIdx.x, i = blockIdx.x * 512 + tid;
    int v = (i < n) ? cnt[i] : 0;
    sd[tid] = v;
    __syncthreads();
    for (int o = 1; o < 512; o <<= 1) {
        int t = (tid >= o) ? sd[tid - o] : 0;
        __syncthreads();
        sd[tid] += t;
        __syncthreads();
    }
    int incl = sd[tid] + bsum[blockIdx.x];
    if (i < n) rp[i] = incl - v;
    if (i == n - 1) rp[n] = incl;
}

// scatter payload into bucket-partitioned tmp (LDS-ranked). Key low 8 bits in
// payload bits 24-31 for the sort pass. unmask stored as replicated half2.
__global__ __launch_bounds__(256) void bucket_scatter_both(
    const int* __restrict__ head, const int* __restrict__ tail,
    const int* __restrict__ etype, const float* __restrict__ unmask,
    const int* __restrict__ irows, const int* __restrict__ icols,
    const int* __restrict__ off, long long* __restrict__ tmp_ev,
    int* __restrict__ tmp_col) {
    __shared__ int h[NB_E];
    __shared__ int boff[NB_E];
    bool isE = blockIdx.x < GA;
    int b = isE ? blockIdx.x : blockIdx.x - GA;
    if (isE) {
        for (int t = threadIdx.x; t < NB_E; t += 256) { h[t] = 0; boff[t] = off[t * GA + b]; }
        __syncthreads();
        int chunk = (N_EDGES + GA - 1) / GA;
        int s = b * chunk;
        int e = N_EDGES < s + chunk ? N_EDGES : s + chunk;
        for (int i = s + threadIdx.x; i < e; i += 256) {
            int k = head[i];
            int bk = k >> 8;
            int local = atomicAdd(&h[bk], 1);
            unsigned hh = __half_as_ushort(__float2half_rn(unmask[i]));
            unsigned hi = hh | (hh << 16);
            unsigned lo = (unsigned)(tail[i] | ((etype[i] - 1) << 20) | ((k & 255) << 24));
            tmp_ev[boff[bk] + local] = (long long)(((unsigned long long)hi << 32) | lo);
        }
    } else {
        for (int t = threadIdx.x; t < NB_U; t += 256) { h[t] = 0; boff[t] = off[NALL_E + t * GA + b] - N_EDGES; }
        __syncthreads();
        int chunk = (NNZ + GA - 1) / GA;
        int s = b * chunk;
        int e = NNZ < s + chunk ? NNZ : s + chunk;
        for (int i = s + threadIdx.x; i < e; i += 256) {
            int k = irows[i];
            int bk = k >> 8;
            int local = atomicAdd(&h[bk], 1);
            tmp_col[boff[bk] + local] = icols[i] | ((k & 255) << 24);
        }
    }
}

// one block per bucket: LDS 256-key hist + scan -> rp; LDS-staged sort;
// coalesced final write with key bits stripped.
__global__ __launch_bounds__(256) void bucket_sort_both(
    const int* __restrict__ off, const long long* __restrict__ tmp_ev,
    const int* __restrict__ tmp_col, long long* __restrict__ ev,
    int* __restrict__ col_s, int* __restrict__ rp_e, int* __restrict__ rp_u) {
    __shared__ int khist[256];
    __shared__ int koff[256];
    __shared__ long long stage[CAP_D];
    int t = threadIdx.x;
    bool isE = blockIdx.x < NB_E;
    if (isE) {
        int b = blockIdx.x;
        int sb = off[b * GA], se = off[(b + 1) * GA];
        int len = se - sb;
        khist[t] = 0;
        __syncthreads();
        for (int i = t; i < len; i += 256)
            atomicAdd(&khist[(int)(((unsigned long long)tmp_ev[sb + i] >> 24) & 255)], 1);
        __syncthreads();
        int v = khist[t];
        koff[t] = v;
        __syncthreads();
        for (int o = 1; o < 256; o <<= 1) {
            int x = (t >= o) ? koff[t - o] : 0;
            __syncthreads();
            koff[t] += x;
            __syncthreads();
        }
        int excl = koff[t] - v;
        int key = b * 256 + t;
        if (key < N_ENT) rp_e[key] = sb + excl;
        if (b == 0 && t == 0) rp_e[N_ENT] = N_EDGES;
        khist[t] = excl;
        __syncthreads();
        if (len <= CAP_D) {
            for (int i = t; i < len; i += 256) {
                long long v2 = tmp_ev[sb + i];
                int k = (int)(((unsigned long long)v2 >> 24) & 255);
                int p = atomicAdd(&khist[k], 1);
                stage[p] = v2;
            }
            __syncthreads();
            for (int i = t; i < len; i += 256)
                ev[sb + i] = stage[i] & (long long)0xFFFFFFFF00FFFFFFULL;
        } else {
            for (int i = t; i < len; i += 256) {
                long long v2 = tmp_ev[sb + i];
                int k = (int)(((unsigned long long)v2 >> 24) & 255);
                int p = atomicAdd(&khist[k], 1);
                ev[sb + p] = v2 & (long long)0xFFFFFFFF00FFFFFFULL;
            }
        }
    } else {
        int b = blockIdx.x - NB_E;
        int sb = off[NALL_E + b * GA] - N_EDGES;
        int se = off[NALL_E + (b + 1) * GA] - N_EDGES;
        int len = se - sb;
        int* stage32 = (int*)stage;
        khist[t] = 0;
        __syncthreads();
        for (int i = t; i < len; i += 256)
            atomicAdd(&khist[(tmp_col[sb + i] >> 24) & 255], 1);
        __syncthreads();
        int v = khist[t];
        koff[t] = v;
        __syncthreads();
        for (int o = 1; o < 256; o <<= 1) {
            int x = (t >= o) ? koff[t - o] : 0;
            __syncthreads();
            koff[t] += x;
            __syncthreads();
        }
        int excl = koff[t] - v;
        int key = b * 256 + t;
        if (key < N_USERS) rp_u[key] = sb + excl;
        if (b == 0 && t == 0) rp_u[N_USERS] = NNZ;
        khist[t] = excl;
        __syncthreads();
        if (len <= CAP_D) {
            for (int i = t; i < len; i += 256) {
                int v2 = tmp_col[sb + i];
                int p = atomicAdd(&khist[(v2 >> 24) & 255], 1);
                stage32[p] = v2;
            }
            __syncthreads();
            for (int i = t; i < len; i += 256)
                col_s[sb + i] = stage32[i] & 0x00FFFFFF;
        } else {
            for (int i = t; i < len; i += 256) {
                int v2 = tmp_col[sb + i];
                int p = atomicAdd(&khist[(v2 >> 24) & 255], 1);
                col_s[sb + p] = v2 & 0x00FFFFFF;
            }
        }
    }
}

// ---------------- fused per-hop aggregate + normalize ----------------
// 2 rows per wave (lanes 0-31 / 32-63); per 32-half: 4 edge slots x 8 lanes,
// unrolled x2 -> 8 edges in flight per row. Packed fp16 math; f32 for the
// normalize + residual. ALL streaming accesses (ev, col_s, hop outputs,
// FINAL residual I/O) are non-temporal so they don't evict the gather table
// from L2; only the entity-table gathers allocate in cache.
// FINAL=0: write fp16 hop output. FINAL=1: fuse res = emb + n1 + n2 + n3.

__device__ inline void edge_body16(const uint4* __restrict__ in16,
                                   const uint4* __restrict__ w16,
                                   int ex, unsigned scbits, int sub, __half2 (&acc)[4]) {
    int tt = ex & 0xFFFFF, rt = (ex >> 20) & 15;
    uint4 r4 = in16[(size_t)tt * 8 + sub];
    uint4 w4 = w16[rt * 8 + sub];
    __half2 sc2 = bits_h2(scbits);
    acc[0] = __hfma2(__hmul2(bits_h2(r4.x), sc2), bits_h2(w4.x), acc[0]);
    acc[1] = __hfma2(__hmul2(bits_h2(r4.y), sc2), bits_h2(w4.y), acc[1]);
    acc[2] = __hfma2(__hmul2(bits_h2(r4.z), sc2), bits_h2(w4.z), acc[2]);
    acc[3] = __hfma2(__hmul2(bits_h2(r4.w), sc2), bits_h2(w4.w), acc[3]);
}

template <int FINAL>
__global__ __launch_bounds__(256) void agg_hop(
    const uint4* __restrict__ in16, const uint4* __restrict__ w16,
    const int* __restrict__ rp_e, const long long* __restrict__ ev,
    const int* __restrict__ rp_u, const int* __restrict__ col_s,
    uint4* __restrict__ oute, uint4* __restrict__ outu,
    const uint4* __restrict__ pe1, const uint4* __restrict__ pu1,
    const uint4* __restrict__ pu2,
    const float4* __restrict__ emb_e, const float4* __restrict__ emb_u,
    float4* __restrict__ res_e, float4* __restrict__ res_u) {
    int gwave = (blockIdx.x * blockDim.x + threadIdx.x) >> 6;
    if (gwave >= HALF_E + HALF_U) return;
    int lane = threadIdx.x & 63;
    int half = lane >> 5;
    int grp = (lane >> 3) & 3;   // edge slot 0..3 within the 32-half
    int sub = lane & 7;          // uint4 index within fp16 row

    bool is_ent = gwave < HALF_E;
    int row = is_ent ? gwave * 2 + half : (gwave - HALF_E) * 2 + half;
    const int* __restrict__ rp = is_ent ? rp_e : rp_u;
    int beg = rp[row], end = rp[row + 1];

    __half2 acc[4];
#pragma unroll
    for (int j = 0; j < 4; ++j) acc[j] = bits_h2(0u);

    if (is_ent) {
        for (int p0 = beg; p0 < end; p0 += 8) {
            int pA = p0 + grp, pB = p0 + 4 + grp;
            long long eA = (pA < end) ? __builtin_nontemporal_load(&ev[pA]) : 0ll;
            long long eB = (pB < end) ? __builtin_nontemporal_load(&ev[pB]) : 0ll;
            edge_body16(in16, w16, (int)(unsigned)eA,
                        (unsigned)((unsigned long long)eA >> 32), sub, acc);
            edge_body16(in16, w16, (int)(unsigned)eB,
                        (unsigned)((unsigned long long)eB >> 32), sub, acc);
        }
    } else {
        for (int p0 = beg; p0 < end; p0 += 8) {
            int pA = p0 + grp, pB = p0 + 4 + grp;
            int cA = 0, cB = 0;
            unsigned mAb = 0u, mBb = 0u;
            if (pA < end) { cA = __builtin_nontemporal_load(&col_s[pA]); mAb = 0x3C003C00u; }
            if (pB < end) { cB = __builtin_nontemporal_load(&col_s[pB]); mBb = 0x3C003C00u; }
            __half2 mA = bits_h2(mAb), mB = bits_h2(mBb);
            {
                uint4 r4 = in16[(size_t)cA * 8 + sub];
                acc[0] = __hfma2(bits_h2(r4.x), mA, acc[0]);
                acc[1] = __hfma2(bits_h2(r4.y), mA, acc[1]);
                acc[2] = __hfma2(bits_h2(r4.z), mA, acc[2]);
                acc[3] = __hfma2(bits_h2(r4.w), mA, acc[3]);
            }
            {
                uint4 r4 = in16[(size_t)cB * 8 + sub];
                acc[0] = __hfma2(bits_h2(r4.x), mB, acc[0]);
                acc[1] = __hfma2(bits_h2(r4.y), mB, acc[1]);
                acc[2] = __hfma2(bits_h2(r4.z), mB, acc[2]);
                acc[3] = __hfma2(bits_h2(r4.w), mB, acc[3]);
            }
        }
    }

    // fold the 4 edge slots (within each 32-half: offsets 8, 16), packed
#pragma unroll
    for (int j = 0; j < 4; ++j) {
        acc[j] = __hadd2(acc[j], shfl_h2(acc[j], 8));
        acc[j] = __hadd2(acc[j], shfl_h2(acc[j], 16));
    }
    // to f32 for normalize
    float2 f0 = __half22float2(acc[0]), f1 = __half22float2(acc[1]);
    float2 f2 = __half22float2(acc[2]), f3 = __half22float2(acc[3]);
    float ss = f0.x * f0.x + f0.y * f0.y + f1.x * f1.x + f1.y * f1.y +
               f2.x * f2.x + f2.y * f2.y + f3.x * f3.x + f3.y * f3.y;
    ss += __shfl_xor(ss, 1, 64);
    ss += __shfl_xor(ss, 2, 64);
    ss += __shfl_xor(ss, 4, 64);
    float inv = 1.0f / fmaxf(sqrtf(ss), 1e-12f);

    if (grp == 0) {
        float n0 = f0.x * inv, n1 = f0.y * inv, n2 = f1.x * inv, n3 = f1.y * inv;
        float n4 = f2.x * inv, n5 = f2.y * inv, n6 = f3.x * inv, n7 = f3.y * inv;
        if constexpr (!FINAL) {
            uint4 p;
            p.x = pack_h2(n0, n1); p.y = pack_h2(n2, n3);
            p.z = pack_h2(n4, n5); p.w = pack_h2(n6, n7);
            nt_store_u4(&(is_ent ? oute : outu)[(size_t)row * 8 + sub], p);
        } else {
            const uint4* q1p = is_ent ? pe1 : pu1;   // hop-1 output
            const uint4* q2p = is_ent ? in16 : pu2;  // hop-2 output (entity: own input)
            uint4 q1 = nt_load_u4(&q1p[(size_t)row * 8 + sub]);
            uint4 q2 = nt_load_u4(&q2p[(size_t)row * 8 + sub]);
            const float4* emb = is_ent ? emb_e : emb_u;
            float4* res = is_ent ? res_e : res_u;
            size_t rb = (size_t)row * 16 + sub * 2;
            float4 a = nt_load_f4(&emb[rb]), b = nt_load_f4(&emb[rb + 1]);
            float2 x0 = unpack_h2(q1.x), x1 = unpack_h2(q1.y);
            float2 x2 = unpack_h2(q1.z), x3 = unpack_h2(q1.w);
            float2 y0 = unpack_h2(q2.x), y1 = unpack_h2(q2.y);
            float2 y2 = unpack_h2(q2.z), y3 = unpack_h2(q2.w);
            a.x += n0 + x0.x + y0.x;  a.y += n1 + x0.y + y0.y;
            a.z += n2 + x1.x + y1.x;  a.w += n3 + x1.y + y1.y;
            b.x += n4 + x2.x + y2.x;  b.y += n5 + x2.y + y2.y;
            b.z += n6 + x3.x + y3.x;  b.w += n7 + x3.y + y3.y;
            nt_store_f4(&res[rb], a);
            nt_store_f4(&res[rb + 1], b);
        }
    }
}

// ---------------- launch ----------------

extern "C" void kernel_launch(void* const* d_in, const int* in_sizes, int n_in,
                              void* d_out, int out_size, void* d_ws, size_t ws_size,
                              hipStream_t stream) {
    const float* user_emb   = (const float*)d_in[0];
    const float* entity_emb = (const float*)d_in[1];
    const float* weight     = (const float*)d_in[2];
    const float* unmask     = (const float*)d_in[3];
    const int*   edge_index = (const int*)d_in[4];
    const int*   edge_type  = (const int*)d_in[5];
    const int*   irows      = (const int*)d_in[6];
    const int*   icols      = (const int*)d_in[7];
    const int* head = edge_index;            // edge_index[0]
    const int* tail = edge_index + N_EDGES;  // edge_index[1]

    char* ws = (char*)d_ws;
    size_t off = 0;
    auto alloc = [&](size_t bytes) -> void* {
        void* p = ws + off;
        off += (bytes + 255) & ~(size_t)255;
        return p;
    };
    uint4* B0     = (uint4*)alloc((size_t)N_ENT * DIM * 2);   // fp16 emb
    uint4* B1     = (uint4*)alloc((size_t)N_ENT * DIM * 2);   // n1 (ent)
    uint4* B2     = (uint4*)alloc((size_t)N_ENT * DIM * 2);   // n2 (ent)
    uint4* U1     = (uint4*)alloc((size_t)N_USERS * DIM * 2); // n1 (usr)
    uint4* U2     = (uint4*)alloc((size_t)N_USERS * DIM * 2); // n2 (usr)
    uint4* w16    = (uint4*)alloc(16 * DIM * 2);
    int*   rp_e   = (int*)alloc((N_ENT + 1) * 4);
    int*   rp_u   = (int*)alloc((N_USERS + 1) * 4);
    long long* ev     = (long long*)alloc((size_t)N_EDGES * 8);
    long long* tmp_ev = (long long*)alloc((size_t)N_EDGES * 8);
    int*   col_s   = (int*)alloc((size_t)NNZ * 4);
    int*   tmp_col = (int*)alloc((size_t)NNZ * 4);
    int*   bh     = (int*)alloc((size_t)(NALL + 1) * 4);
    int*   offA   = (int*)alloc((size_t)(NALL + 1) * 4);
    int*   bs     = (int*)alloc(1024 * 4);
    (void)ws_size;

    // --- fp16 conversions (independent of CSR build) ---
    f32_to_f16<<<(N_ENT * DIM / 8 + 255) / 256, 256, 0, stream>>>(
        (const float4*)entity_emb, B0, N_ENT * DIM / 8);
    f32_to_f16<<<1, 128, 0, stream>>>((const float4*)weight, w16, 16 * DIM / 8);

    // --- CSR build: merged two-level LDS counting sort ---
    bucket_hist_both<<<2 * GA, 256, 0, stream>>>(head, irows, bh);
    scan_partial<<<NB_SCAN, 512, 0, stream>>>(bh, NALL, bs);
    scan_bsum<<<1, 1024, 0, stream>>>(bs, NB_SCAN);
    scan_final<<<NB_SCAN, 512, 0, stream>>>(bh, NALL, bs, offA);
    bucket_scatter_both<<<2 * GA, 256, 0, stream>>>(
        head, tail, edge_type, unmask, irows, icols, offA, tmp_ev, tmp_col);
    bucket_sort_both<<<NB_E + NB_U, 256, 0, stream>>>(
        offA, tmp_ev, tmp_col, ev, col_s, rp_e, rp_u);

    // --- 3 hops: h0,h1 write fp16 outputs; h2 fuses residual sum ---
    float* res_e = (float*)d_out;
    float* res_u = res_e + (size_t)N_ENT * DIM;
    int grid_agg = ((HALF_E + HALF_U) * 64 + 255) / 256;

    agg_hop<0><<<grid_agg, 256, 0, stream>>>(
        B0, w16, rp_e, ev, rp_u, col_s, B1, U1,
        nullptr, nullptr, nullptr, nullptr, nullptr, nullptr, nullptr);
    agg_hop<0><<<grid_agg, 256, 0, stream>>>(
        B1, w16, rp_e, ev, rp_u, col_s, B2, U2,
        nullptr, nullptr, nullptr, nullptr, nullptr, nullptr, nullptr);
    agg_hop<1><<<grid_agg, 256, 0, stream>>>(
        B2, w16, rp_e, ev, rp_u, col_s, nullptr, nullptr,
        B1, U1, U2,
        (const float4*)entity_emb, (const float4*)user_emb,
        (float4*)res_e, (float4*)res_u);
}

// Round 12
// 247.272 us; speedup vs baseline: 1.1523x; 1.1523x over previous
//
#include <hip/hip_runtime.h>
#include <hip/hip_fp16.h>
#include <math.h>

#define N_USERS   50000
#define N_ENT     100000
#define N_EDGES   2000000
#define NNZ       1000000
#define DIM       64
#define HALF_E    (N_ENT / 2)
#define HALF_U    (N_USERS / 2)

#define GA      512                    // blocks per side for bucket hist/scatter
#define NB_E    391                    // coarse buckets (256 keys each) entity
#define NB_U    196                    // user
#define NALL_E  (NB_E * GA)            // 200192
#define NALL_U  (NB_U * GA)            // 100352
#define NALL    (NALL_E + NALL_U)      // 300544
#define NB_SCAN (NALL / 512)           // 587 (exact)
#define CAP_D   6400                   // bucket capacity (mean 5120 + 18 sigma)

// ---------------- helpers ----------------

__device__ inline unsigned pack_h2(float x, float y) {
    unsigned lo = __half_as_ushort(__float2half_rn(x));
    unsigned hi = __half_as_ushort(__float2half_rn(y));
    return lo | (hi << 16);
}

__device__ inline float2 unpack_h2(unsigned u) {
    __half2 h = *reinterpret_cast<__half2*>(&u);
    return __half22float2(h);
}

__device__ inline __half2 bits_h2(unsigned u) { return *reinterpret_cast<__half2*>(&u); }

__device__ inline __half2 shfl_h2(__half2 v, int o) {
    int x = *reinterpret_cast<int*>(&v);
    x = __shfl_xor(x, o, 64);
    return *reinterpret_cast<__half2*>(&x);
}

// f32 -> packed fp16 (uint4 = 8 halves from 2 float4)
__global__ void f32_to_f16(const float4* __restrict__ in, uint4* __restrict__ out, int n4) {
    int i = blockIdx.x * blockDim.x + threadIdx.x;
    if (i < n4) {
        float4 a = in[2 * i], b = in[2 * i + 1];
        uint4 o;
        o.x = pack_h2(a.x, a.y);
        o.y = pack_h2(a.z, a.w);
        o.z = pack_h2(b.x, b.y);
        o.w = pack_h2(b.z, b.w);
        out[i] = o;
    }
}

// ---------------- CSR build: two-level LDS counting sort (no global atomics) ----------------
// Coarse bucket = key >> 8. E and U sides merged per pass.

__global__ __launch_bounds__(256) void bucket_hist_both(
    const int* __restrict__ head, const int* __restrict__ irows, int* __restrict__ bh) {
    __shared__ int h[NB_E];
    bool isE = blockIdx.x < GA;
    int b = isE ? blockIdx.x : blockIdx.x - GA;
    const int* key = isE ? head : irows;
    int n = isE ? N_EDGES : NNZ;
    int nbuck = isE ? NB_E : NB_U;
    int base = isE ? 0 : NALL_E;
    for (int t = threadIdx.x; t < nbuck; t += 256) h[t] = 0;
    __syncthreads();
    int chunk = (n + GA - 1) / GA;
    int s = b * chunk;
    int e = n < s + chunk ? n : s + chunk;
    for (int i = s + threadIdx.x; i < e; i += 256)
        atomicAdd(&h[key[i] >> 8], 1);
    __syncthreads();
    for (int t = threadIdx.x; t < nbuck; t += 256)
        bh[base + t * GA + b] = h[t];
}

// 3-kernel exclusive scan over the concatenated count array (512-thr blocks)
__global__ void scan_partial(const int* __restrict__ cnt, int n, int* __restrict__ bsum) {
    __shared__ int sd[512];
    int tid = threadIdx.x, i = blockIdx.x * 512 + tid;
    sd[tid] = (i < n) ? cnt[i] : 0;
    __syncthreads();
    for (int s = 256; s > 0; s >>= 1) {
        if (tid < s) sd[tid] += sd[tid + s];
        __syncthreads();
    }
    if (tid == 0) bsum[blockIdx.x] = sd[0];
}

__global__ void scan_bsum(int* bsum, int nb) {
    __shared__ int sd[1024];
    int tid = threadIdx.x;
    int v = (tid < nb) ? bsum[tid] : 0;
    sd[tid] = v;
    __syncthreads();
    for (int o = 1; o < 1024; o <<= 1) {
        int t = (tid >= o) ? sd[tid - o] : 0;
        __syncthreads();
        sd[tid] += t;
        __syncthreads();
    }
    if (tid < nb) bsum[tid] = sd[tid] - v;  // exclusive
}

__global__ void scan_final(const int* __restrict__ cnt, int n,
                           const int* __restrict__ bsum, int* __restrict__ rp) {
    __shared__ int sd[512];
    int tid = threadIdx.x, i = blockIdx.x * 512 + tid;
    int v = (i < n) ? cnt[i] : 0;
    sd[tid] = v;
    __syncthreads();
    for (int o = 1; o < 512; o <<= 1) {
        int t = (tid >= o) ? sd[tid - o] : 0;
        __syncthreads();
        sd[tid] += t;
        __syncthreads();
    }
    int incl = sd[tid] + bsum[blockIdx.x];
    if (i < n) rp[i] = incl - v;
    if (i == n - 1) rp[n] = incl;
}

// scatter payload into bucket-partitioned tmp (LDS-ranked). Key low 8 bits in
// payload bits 24-31 for the sort pass. unmask stored as replicated half2.
__global__ __launch_bounds__(256) void bucket_scatter_both(
    const int* __restrict__ head, const int* __restrict__ tail,
    const int* __restrict__ etype, const float* __restrict__ unmask,
    const int* __restrict__ irows, const int* __restrict__ icols,
    const int* __restrict__ off, long long* __restrict__ tmp_ev,
    int* __restrict__ tmp_col) {
    __shared__ int h[NB_E];
    __shared__ int boff[NB_E];
    bool isE = blockIdx.x < GA;
    int b = isE ? blockIdx.x : blockIdx.x - GA;
    if (isE) {
        for (int t = threadIdx.x; t < NB_E; t += 256) { h[t] = 0; boff[t] = off[t * GA + b]; }
        __syncthreads();
        int chunk = (N_EDGES + GA - 1) / GA;
        int s = b * chunk;
        int e = N_EDGES < s + chunk ? N_EDGES : s + chunk;
        for (int i = s + threadIdx.x; i < e; i += 256) {
            int k = head[i];
            int bk = k >> 8;
            int local = atomicAdd(&h[bk], 1);
            unsigned hh = __half_as_ushort(__float2half_rn(unmask[i]));
            unsigned hi = hh | (hh << 16);
            unsigned lo = (unsigned)(tail[i] | ((etype[i] - 1) << 20) | ((k & 255) << 24));
            tmp_ev[boff[bk] + local] = (long long)(((unsigned long long)hi << 32) | lo);
        }
    } else {
        for (int t = threadIdx.x; t < NB_U; t += 256) { h[t] = 0; boff[t] = off[NALL_E + t * GA + b] - N_EDGES; }
        __syncthreads();
        int chunk = (NNZ + GA - 1) / GA;
        int s = b * chunk;
        int e = NNZ < s + chunk ? NNZ : s + chunk;
        for (int i = s + threadIdx.x; i < e; i += 256) {
            int k = irows[i];
            int bk = k >> 8;
            int local = atomicAdd(&h[bk], 1);
            tmp_col[boff[bk] + local] = icols[i] | ((k & 255) << 24);
        }
    }
}

// one block per bucket: LDS 256-key hist + scan -> rp; LDS-staged sort;
// coalesced final write with key bits stripped.
__global__ __launch_bounds__(256) void bucket_sort_both(
    const int* __restrict__ off, const long long* __restrict__ tmp_ev,
    const int* __restrict__ tmp_col, long long* __restrict__ ev,
    int* __restrict__ col_s, int* __restrict__ rp_e, int* __restrict__ rp_u) {
    __shared__ int khist[256];
    __shared__ int koff[256];
    __shared__ long long stage[CAP_D];
    int t = threadIdx.x;
    bool isE = blockIdx.x < NB_E;
    if (isE) {
        int b = blockIdx.x;
        int sb = off[b * GA], se = off[(b + 1) * GA];
        int len = se - sb;
        khist[t] = 0;
        __syncthreads();
        for (int i = t; i < len; i += 256)
            atomicAdd(&khist[(int)(((unsigned long long)tmp_ev[sb + i] >> 24) & 255)], 1);
        __syncthreads();
        int v = khist[t];
        koff[t] = v;
        __syncthreads();
        for (int o = 1; o < 256; o <<= 1) {
            int x = (t >= o) ? koff[t - o] : 0;
            __syncthreads();
            koff[t] += x;
            __syncthreads();
        }
        int excl = koff[t] - v;
        int key = b * 256 + t;
        if (key < N_ENT) rp_e[key] = sb + excl;
        if (b == 0 && t == 0) rp_e[N_ENT] = N_EDGES;
        khist[t] = excl;
        __syncthreads();
        if (len <= CAP_D) {
            for (int i = t; i < len; i += 256) {
                long long v2 = tmp_ev[sb + i];
                int k = (int)(((unsigned long long)v2 >> 24) & 255);
                int p = atomicAdd(&khist[k], 1);
                stage[p] = v2;
            }
            __syncthreads();
            for (int i = t; i < len; i += 256)
                ev[sb + i] = stage[i] & (long long)0xFFFFFFFF00FFFFFFULL;
        } else {
            for (int i = t; i < len; i += 256) {
                long long v2 = tmp_ev[sb + i];
                int k = (int)(((unsigned long long)v2 >> 24) & 255);
                int p = atomicAdd(&khist[k], 1);
                ev[sb + p] = v2 & (long long)0xFFFFFFFF00FFFFFFULL;
            }
        }
    } else {
        int b = blockIdx.x - NB_E;
        int sb = off[NALL_E + b * GA] - N_EDGES;
        int se = off[NALL_E + (b + 1) * GA] - N_EDGES;
        int len = se - sb;
        int* stage32 = (int*)stage;
        khist[t] = 0;
        __syncthreads();
        for (int i = t; i < len; i += 256)
            atomicAdd(&khist[(tmp_col[sb + i] >> 24) & 255], 1);
        __syncthreads();
        int v = khist[t];
        koff[t] = v;
        __syncthreads();
        for (int o = 1; o < 256; o <<= 1) {
            int x = (t >= o) ? koff[t - o] : 0;
            __syncthreads();
            koff[t] += x;
            __syncthreads();
        }
        int excl = koff[t] - v;
        int key = b * 256 + t;
        if (key < N_USERS) rp_u[key] = sb + excl;
        if (b == 0 && t == 0) rp_u[N_USERS] = NNZ;
        khist[t] = excl;
        __syncthreads();
        if (len <= CAP_D) {
            for (int i = t; i < len; i += 256) {
                int v2 = tmp_col[sb + i];
                int p = atomicAdd(&khist[(v2 >> 24) & 255], 1);
                stage32[p] = v2;
            }
            __syncthreads();
            for (int i = t; i < len; i += 256)
                col_s[sb + i] = stage32[i] & 0x00FFFFFF;
        } else {
            for (int i = t; i < len; i += 256) {
                int v2 = tmp_col[sb + i];
                int p = atomicAdd(&khist[(v2 >> 24) & 255], 1);
                col_s[sb + p] = v2 & 0x00FFFFFF;
            }
        }
    }
}

// ---------------- fused per-hop aggregate + normalize ----------------
// 2 rows per wave (lanes 0-31 / 32-63); per 32-half: 4 edge slots x 8 lanes,
// unrolled x2 -> 8 edges in flight per row. Packed fp16 math; f32 only for
// the per-row normalize + residual.
// FINAL=0: write fp16 hop output. FINAL=1: fuse res = emb + n1 + n2 + n3.

__device__ inline void edge_body16(const uint4* __restrict__ in16,
                                   const uint4* __restrict__ w16,
                                   int ex, unsigned scbits, int sub, __half2 (&acc)[4]) {
    int tt = ex & 0xFFFFF, rt = (ex >> 20) & 15;
    uint4 r4 = in16[(size_t)tt * 8 + sub];
    uint4 w4 = w16[rt * 8 + sub];
    __half2 sc2 = bits_h2(scbits);
    acc[0] = __hfma2(__hmul2(bits_h2(r4.x), sc2), bits_h2(w4.x), acc[0]);
    acc[1] = __hfma2(__hmul2(bits_h2(r4.y), sc2), bits_h2(w4.y), acc[1]);
    acc[2] = __hfma2(__hmul2(bits_h2(r4.z), sc2), bits_h2(w4.z), acc[2]);
    acc[3] = __hfma2(__hmul2(bits_h2(r4.w), sc2), bits_h2(w4.w), acc[3]);
}

template <int FINAL>
__global__ __launch_bounds__(256) void agg_hop(
    const uint4* __restrict__ in16, const uint4* __restrict__ w16,
    const int* __restrict__ rp_e, const int2* __restrict__ ev,
    const int* __restrict__ rp_u, const int* __restrict__ col_s,
    uint4* __restrict__ oute, uint4* __restrict__ outu,
    const uint4* __restrict__ pe1, const uint4* __restrict__ pu1,
    const uint4* __restrict__ pu2,
    const float4* __restrict__ emb_e, const float4* __restrict__ emb_u,
    float4* __restrict__ res_e, float4* __restrict__ res_u) {
    int gwave = (blockIdx.x * blockDim.x + threadIdx.x) >> 6;
    if (gwave >= HALF_E + HALF_U) return;
    int lane = threadIdx.x & 63;
    int half = lane >> 5;
    int grp = (lane >> 3) & 3;   // edge slot 0..3 within the 32-half
    int sub = lane & 7;          // uint4 index within fp16 row

    bool is_ent = gwave < HALF_E;
    int row = is_ent ? gwave * 2 + half : (gwave - HALF_E) * 2 + half;
    const int* __restrict__ rp = is_ent ? rp_e : rp_u;
    int beg = rp[row], end = rp[row + 1];

    __half2 acc[4];
#pragma unroll
    for (int j = 0; j < 4; ++j) acc[j] = bits_h2(0u);

    if (is_ent) {
        for (int p0 = beg; p0 < end; p0 += 8) {
            int pA = p0 + grp, pB = p0 + 4 + grp;
            int2 eA = (pA < end) ? ev[pA] : make_int2(0, 0);
            int2 eB = (pB < end) ? ev[pB] : make_int2(0, 0);
            edge_body16(in16, w16, eA.x, (unsigned)eA.y, sub, acc);
            edge_body16(in16, w16, eB.x, (unsigned)eB.y, sub, acc);
        }
    } else {
        for (int p0 = beg; p0 < end; p0 += 8) {
            int pA = p0 + grp, pB = p0 + 4 + grp;
            int cA = 0, cB = 0;
            unsigned mAb = 0u, mBb = 0u;
            if (pA < end) { cA = col_s[pA]; mAb = 0x3C003C00u; }
            if (pB < end) { cB = col_s[pB]; mBb = 0x3C003C00u; }
            __half2 mA = bits_h2(mAb), mB = bits_h2(mBb);
            {
                uint4 r4 = in16[(size_t)cA * 8 + sub];
                acc[0] = __hfma2(bits_h2(r4.x), mA, acc[0]);
                acc[1] = __hfma2(bits_h2(r4.y), mA, acc[1]);
                acc[2] = __hfma2(bits_h2(r4.z), mA, acc[2]);
                acc[3] = __hfma2(bits_h2(r4.w), mA, acc[3]);
            }
            {
                uint4 r4 = in16[(size_t)cB * 8 + sub];
                acc[0] = __hfma2(bits_h2(r4.x), mB, acc[0]);
                acc[1] = __hfma2(bits_h2(r4.y), mB, acc[1]);
                acc[2] = __hfma2(bits_h2(r4.z), mB, acc[2]);
                acc[3] = __hfma2(bits_h2(r4.w), mB, acc[3]);
            }
        }
    }

    // fold the 4 edge slots (within each 32-half: offsets 8, 16), packed
#pragma unroll
    for (int j = 0; j < 4; ++j) {
        acc[j] = __hadd2(acc[j], shfl_h2(acc[j], 8));
        acc[j] = __hadd2(acc[j], shfl_h2(acc[j], 16));
    }
    // to f32 for normalize
    float2 f0 = __half22float2(acc[0]), f1 = __half22float2(acc[1]);
    float2 f2 = __half22float2(acc[2]), f3 = __half22float2(acc[3]);
    float ss = f0.x * f0.x + f0.y * f0.y + f1.x * f1.x + f1.y * f1.y +
               f2.x * f2.x + f2.y * f2.y + f3.x * f3.x + f3.y * f3.y;
    ss += __shfl_xor(ss, 1, 64);
    ss += __shfl_xor(ss, 2, 64);
    ss += __shfl_xor(ss, 4, 64);
    float inv = 1.0f / fmaxf(sqrtf(ss), 1e-12f);

    if (grp == 0) {
        float n0 = f0.x * inv, n1 = f0.y * inv, n2 = f1.x * inv, n3 = f1.y * inv;
        float n4 = f2.x * inv, n5 = f2.y * inv, n6 = f3.x * inv, n7 = f3.y * inv;
        if constexpr (!FINAL) {
            uint4 p;
            p.x = pack_h2(n0, n1); p.y = pack_h2(n2, n3);
            p.z = pack_h2(n4, n5); p.w = pack_h2(n6, n7);
            (is_ent ? oute : outu)[(size_t)row * 8 + sub] = p;
        } else {
            const uint4* q1p = is_ent ? pe1 : pu1;   // hop-1 output
            const uint4* q2p = is_ent ? in16 : pu2;  // hop-2 output (entity: own input)
            uint4 q1 = q1p[(size_t)row * 8 + sub];
            uint4 q2 = q2p[(size_t)row * 8 + sub];
            const float4* emb = is_ent ? emb_e : emb_u;
            float4* res = is_ent ? res_e : res_u;
            size_t rb = (size_t)row * 16 + sub * 2;
            float4 a = emb[rb], b = emb[rb + 1];
            float2 x0 = unpack_h2(q1.x), x1 = unpack_h2(q1.y);
            float2 x2 = unpack_h2(q1.z), x3 = unpack_h2(q1.w);
            float2 y0 = unpack_h2(q2.x), y1 = unpack_h2(q2.y);
            float2 y2 = unpack_h2(q2.z), y3 = unpack_h2(q2.w);
            a.x += n0 + x0.x + y0.x;  a.y += n1 + x0.y + y0.y;
            a.z += n2 + x1.x + y1.x;  a.w += n3 + x1.y + y1.y;
            b.x += n4 + x2.x + y2.x;  b.y += n5 + x2.y + y2.y;
            b.z += n6 + x3.x + y3.x;  b.w += n7 + x3.y + y3.y;
            res[rb] = a;
            res[rb + 1] = b;
        }
    }
}

// ---------------- launch ----------------

extern "C" void kernel_launch(void* const* d_in, const int* in_sizes, int n_in,
                              void* d_out, int out_size, void* d_ws, size_t ws_size,
                              hipStream_t stream) {
    const float* user_emb   = (const float*)d_in[0];
    const float* entity_emb = (const float*)d_in[1];
    const float* weight     = (const float*)d_in[2];
    const float* unmask     = (const float*)d_in[3];
    const int*   edge_index = (const int*)d_in[4];
    const int*   edge_type  = (const int*)d_in[5];
    const int*   irows      = (const int*)d_in[6];
    const int*   icols      = (const int*)d_in[7];
    const int* head = edge_index;            // edge_index[0]
    const int* tail = edge_index + N_EDGES;  // edge_index[1]

    char* ws = (char*)d_ws;
    size_t off = 0;
    auto alloc = [&](size_t bytes) -> void* {
        void* p = ws + off;
        off += (bytes + 255) & ~(size_t)255;
        return p;
    };
    uint4* B0     = (uint4*)alloc((size_t)N_ENT * DIM * 2);   // fp16 emb
    uint4* B1     = (uint4*)alloc((size_t)N_ENT * DIM * 2);   // n1 (ent)
    uint4* B2     = (uint4*)alloc((size_t)N_ENT * DIM * 2);   // n2 (ent)
    uint4* U1     = (uint4*)alloc((size_t)N_USERS * DIM * 2); // n1 (usr)
    uint4* U2     = (uint4*)alloc((size_t)N_USERS * DIM * 2); // n2 (usr)
    uint4* w16    = (uint4*)alloc(16 * DIM * 2);
    int*   rp_e   = (int*)alloc((N_ENT + 1) * 4);
    int*   rp_u   = (int*)alloc((N_USERS + 1) * 4);
    long long* ev     = (long long*)alloc((size_t)N_EDGES * 8);
    long long* tmp_ev = (long long*)alloc((size_t)N_EDGES * 8);
    int*   col_s   = (int*)alloc((size_t)NNZ * 4);
    int*   tmp_col = (int*)alloc((size_t)NNZ * 4);
    int*   bh     = (int*)alloc((size_t)(NALL + 1) * 4);
    int*   offA   = (int*)alloc((size_t)(NALL + 1) * 4);
    int*   bs     = (int*)alloc(1024 * 4);
    (void)ws_size;

    // --- fp16 conversions (independent of CSR build) ---
    f32_to_f16<<<(N_ENT * DIM / 8 + 255) / 256, 256, 0, stream>>>(
        (const float4*)entity_emb, B0, N_ENT * DIM / 8);
    f32_to_f16<<<1, 128, 0, stream>>>((const float4*)weight, w16, 16 * DIM / 8);

    // --- CSR build: merged two-level LDS counting sort ---
    bucket_hist_both<<<2 * GA, 256, 0, stream>>>(head, irows, bh);
    scan_partial<<<NB_SCAN, 512, 0, stream>>>(bh, NALL, bs);
    scan_bsum<<<1, 1024, 0, stream>>>(bs, NB_SCAN);
    scan_final<<<NB_SCAN, 512, 0, stream>>>(bh, NALL, bs, offA);
    bucket_scatter_both<<<2 * GA, 256, 0, stream>>>(
        head, tail, edge_type, unmask, irows, icols, offA, tmp_ev, tmp_col);
    bucket_sort_both<<<NB_E + NB_U, 256, 0, stream>>>(
        offA, tmp_ev, tmp_col, ev, col_s, rp_e, rp_u);

    // --- 3 hops: h0,h1 write fp16 outputs; h2 fuses residual sum ---
    float* res_e = (float*)d_out;
    float* res_u = res_e + (size_t)N_ENT * DIM;
    int grid_agg = ((HALF_E + HALF_U) * 64 + 255) / 256;

    agg_hop<0><<<grid_agg, 256, 0, stream>>>(
        B0, w16, rp_e, (const int2*)ev, rp_u, col_s, B1, U1,
        nullptr, nullptr, nullptr, nullptr, nullptr, nullptr, nullptr);
    agg_hop<0><<<grid_agg, 256, 0, stream>>>(
        B1, w16, rp_e, (const int2*)ev, rp_u, col_s, B2, U2,
        nullptr, nullptr, nullptr, nullptr, nullptr, nullptr, nullptr);
    agg_hop<1><<<grid_agg, 256, 0, stream>>>(
        B2, w16, rp_e, (const int2*)ev, rp_u, col_s, nullptr, nullptr,
        B1, U1, U2,
        (const float4*)entity_emb, (const float4*)user_emb,
        (float4*)res_e, (float4*)res_u);
}